// Round 5
// baseline (758.235 us; speedup 1.0000x reference)
//
#include <hip/hip_runtime.h>
#include <hip/hip_bf16.h>

#define NN 100000
#define EE 1600000
#define HID 128
#define NEG 0.2f
#define CAP 64   // fixed CSR capacity per node (avg deg 16, P(deg>64) ~ 1e-19)

typedef __attribute__((ext_vector_type(8))) short short8;
typedef __attribute__((ext_vector_type(4))) float f32x4;

// ---------------- projection GEMM: xph = bf16(x @ proj_w + b) ----------------
__global__ __launch_bounds__(256) void k_proj(const float* __restrict__ x,
    const float* __restrict__ w, const float* __restrict__ bias,
    __hip_bfloat162* __restrict__ xph) {
  __shared__ float xs[64][32];
  __shared__ float ws[32][128];
  const int tid = threadIdx.x;
  const int row0 = blockIdx.x * 64;
  const int cb = (tid & 31) * 4;   // col base (0..124)
  const int rb = (tid >> 5) * 8;   // row base (0..56)
  float acc[8][4] = {};
  for (int k0 = 0; k0 < 256; k0 += 32) {
    {
      int f = tid * 8;
      int r = f >> 5, c = f & 31;
      int rg = row0 + r;
      float4 v0 = make_float4(0.f, 0.f, 0.f, 0.f), v1 = v0;
      if (rg < NN) {
        const float4* src = (const float4*)&x[(size_t)rg * 256 + k0 + c];
        v0 = src[0];
        v1 = src[1];
      }
      *(float4*)&xs[r][c] = v0;
      *(float4*)&xs[r][c + 4] = v1;
    }
    {
      int f = tid * 16;
      int r = f >> 7, c = f & 127;
      const float4* src = (const float4*)&w[(size_t)(k0 + r) * 128 + c];
      float4 a0 = src[0], a1 = src[1], a2 = src[2], a3 = src[3];
      *(float4*)&ws[r][c] = a0;
      *(float4*)&ws[r][c + 4] = a1;
      *(float4*)&ws[r][c + 8] = a2;
      *(float4*)&ws[r][c + 12] = a3;
    }
    __syncthreads();
#pragma unroll
    for (int kk = 0; kk < 32; kk++) {
      float4 wv = *(const float4*)&ws[kk][cb];
#pragma unroll
      for (int r = 0; r < 8; r++) {
        float a = xs[rb + r][kk];
        acc[r][0] = fmaf(a, wv.x, acc[r][0]);
        acc[r][1] = fmaf(a, wv.y, acc[r][1]);
        acc[r][2] = fmaf(a, wv.z, acc[r][2]);
        acc[r][3] = fmaf(a, wv.w, acc[r][3]);
      }
    }
    __syncthreads();
  }
  float4 bv = *(const float4*)&bias[cb];
#pragma unroll
  for (int r = 0; r < 8; r++) {
    int rg = row0 + rb + r;
    if (rg < NN) {
      float4 o;
      o.x = acc[r][0] + bv.x;
      o.y = acc[r][1] + bv.y;
      o.z = acc[r][2] + bv.z;
      o.w = acc[r][3] + bv.w;
      __hip_bfloat162 b01 = __float22bfloat162_rn(make_float2(o.x, o.y));
      __hip_bfloat162 b23 = __float22bfloat162_rn(make_float2(o.z, o.w));
      *(uint2*)&xph[(size_t)rg * 64 + (cb >> 1)] =
          make_uint2(*(unsigned*)&b01, *(unsigned*)&b23);
    }
  }
}

// ---------------- per-node attention logits (bf16 xph) ----------------
__global__ __launch_bounds__(256) void k_alpha(const __hip_bfloat162* __restrict__ xph,
    const float* __restrict__ a0s, const float* __restrict__ a0d,
    const float* __restrict__ a1s, const float* __restrict__ a1d,
    float* __restrict__ as0, float* __restrict__ ad0,
    float* __restrict__ as1, float* __restrict__ ad1) {
  const int lane = threadIdx.x & 63;
  const int node = blockIdx.x * 4 + (threadIdx.x >> 6);
  if (node >= NN) return;
  float2 v = __bfloat1622float2(xph[(size_t)node * 64 + lane]);
  int i0 = 2 * lane;
  float p0 = v.x * a0s[i0] + v.y * a0s[i0 + 1];
  float p1 = v.x * a0d[i0] + v.y * a0d[i0 + 1];
  float p2 = v.x * a1s[i0] + v.y * a1s[i0 + 1];
  float p3 = v.x * a1d[i0] + v.y * a1d[i0 + 1];
#pragma unroll
  for (int off = 1; off < 8; off <<= 1) {
    p0 += __shfl_xor(p0, off, 64);
    p1 += __shfl_xor(p1, off, 64);
    p2 += __shfl_xor(p2, off, 64);
    p3 += __shfl_xor(p3, off, 64);
  }
  if ((lane & 7) == 0) {
    int h = lane >> 3;
    as0[node * 8 + h] = p0;
    ad0[node * 8 + h] = p1;
    as1[node * 8 + h] = p2;
    ad1[node * 8 + h] = p3;
  }
}

// ---------------- direct scatter into fixed-capacity CSR ----------------
// 1 edge per thread: scatter is latency/masked-write bound (VALUBusy<1%), so
// thread count IS the memory-level parallelism. (4 edges/thread was 1.7x slower.)
__global__ __launch_bounds__(256) void k_scatter(const int* __restrict__ ei0,
    const int* __restrict__ ei1, int* __restrict__ cnt, int* __restrict__ csr) {
  const int p = blockIdx.y;
  const int e = blockIdx.x * 256 + threadIdx.x;
  if (e >= EE) return;
  const int* __restrict__ ei = p ? ei1 : ei0;
  int* __restrict__ c = cnt + p * NN;
  int* __restrict__ out = csr + (size_t)p * NN * CAP;
  int s = ei[e];
  int d = ei[EE + e];
  int pos = atomicAdd(&c[d], 1);
  if (pos < CAP) __builtin_nontemporal_store(s, &out[d * CAP + pos]);
}

// ---------------- GAT aggregation: single-pass, one wave per dst node ----------
#define LRELU(t) ((t) > 0.f ? (t) : NEG * (t))

#define EDGE_BODY(sv)                                      \
  {                                                        \
    unsigned s = (unsigned)(sv);                           \
    float t = asrc[s * 8u + h];                            \
    __hip_bfloat162 v = xph[s * 64u + lane];               \
    float al = __expf(LRELU(t + ad));                      \
    denom += al;                                           \
    float2 f = __bfloat1622float2(v);                      \
    a0 = fmaf(al, f.x, a0);                                \
    a1 = fmaf(al, f.y, a1);                                \
  }

__global__ __launch_bounds__(256) void k_aggr(const __hip_bfloat162* __restrict__ xph,
    const float* __restrict__ as0, const float* __restrict__ ad0,
    const float* __restrict__ as1, const float* __restrict__ ad1,
    const int* __restrict__ cnt, const int* __restrict__ csr,
    __hip_bfloat162* __restrict__ h0, __hip_bfloat162* __restrict__ h1) {
  const int p = blockIdx.y;
  const unsigned lane = threadIdx.x & 63;
  const int node = blockIdx.x * 4 + (threadIdx.x >> 6);
  if (node >= NN) return;
  const float* __restrict__ asrc = p ? as1 : as0;
  const float* __restrict__ adst = p ? ad1 : ad0;
  const int* __restrict__ cs = csr + ((size_t)p * NN + node) * CAP;
  __hip_bfloat162* __restrict__ hout = p ? h1 : h0;
  const unsigned h = lane >> 3;
  const float ad = adst[(unsigned)node * 8u + h];
  const int deg = min(cnt[p * NN + node], CAP);

  float denom = 1e-16f, a0 = 0.f, a1 = 0.f;
  int e = 0;
  for (; e + 8 <= deg; e += 8) {
    int4 q0 = *(const int4*)&cs[e];       // wave-uniform -> scalar loads
    int4 q1 = *(const int4*)&cs[e + 4];
    EDGE_BODY(q0.x) EDGE_BODY(q0.y) EDGE_BODY(q0.z) EDGE_BODY(q0.w)
    EDGE_BODY(q1.x) EDGE_BODY(q1.y) EDGE_BODY(q1.z) EDGE_BODY(q1.w)
  }
  for (; e + 4 <= deg; e += 4) {
    int4 q0 = *(const int4*)&cs[e];
    EDGE_BODY(q0.x) EDGE_BODY(q0.y) EDGE_BODY(q0.z) EDGE_BODY(q0.w)
  }
  for (; e < deg; e++) EDGE_BODY(cs[e])
  float inv = 1.f / denom;
  hout[(size_t)node * 64 + lane] =
      __float22bfloat162_rn(make_float2(fmaxf(a0 * inv, 0.f), fmaxf(a1 * inv, 0.f)));
}

// ---------------- semantic attention via MFMA ----------------
#define KWS 136
#define NTILES ((NN + 63) / 64)
#define SEMGX 256

__global__ __launch_bounds__(256) void k_sem(const __hip_bfloat16* __restrict__ h0,
    const __hip_bfloat16* __restrict__ h1, const float* __restrict__ kw,
    const float* __restrict__ kb, float* __restrict__ ksum) {
  __shared__ short kwT[128 * KWS];
  __shared__ float red[4][128];
  const int tid = threadIdx.x;
  const int m = blockIdx.y;
  const short* __restrict__ hc = (const short*)(m ? h1 : h0);
  for (int l = tid; l < 128 * 128; l += 256) {
    int i = l >> 7, j = l & 127;   // kw[i][j] -> kwT[j][i]
    __hip_bfloat16 bv = __float2bfloat16(kw[l]);
    kwT[j * KWS + i] = *(short*)&bv;
  }
  const int lane = tid & 63;
  const int wave = tid >> 6;
  const int rowgrp = lane >> 4;
  const int lcol = lane & 15;
  float partial[8] = {};
  float kbv[8];
#pragma unroll
  for (int ct = 0; ct < 8; ct++) kbv[ct] = kb[ct * 16 + lcol];
  __syncthreads();
  for (int tile = blockIdx.x; tile < NTILES; tile += SEMGX) {
    int n0 = tile * 64 + wave * 16;
    int row = n0 + lcol;
    if (row >= NN) row = 0;
    const short* hr = hc + (size_t)row * 128 + rowgrp * 8;
    short8 afrag[4];
#pragma unroll
    for (int kc = 0; kc < 4; kc++) afrag[kc] = *(const short8*)(hr + kc * 32);
#pragma unroll
    for (int ct = 0; ct < 8; ct++) {
      f32x4 acc = {0.f, 0.f, 0.f, 0.f};
#pragma unroll
      for (int kc = 0; kc < 4; kc++) {
        short8 bfrag = *(const short8*)&kwT[(ct * 16 + lcol) * KWS + kc * 32 + rowgrp * 8];
        acc = __builtin_amdgcn_mfma_f32_16x16x32_bf16(afrag[kc], bfrag, acc, 0, 0, 0);
      }
#pragma unroll
      for (int r = 0; r < 4; r++) {
        int node = n0 + rowgrp * 4 + r;
        if (node < NN) partial[ct] += tanhf(acc[r] + kbv[ct]);
      }
    }
  }
#pragma unroll
  for (int ct = 0; ct < 8; ct++) {
    partial[ct] += __shfl_xor(partial[ct], 16, 64);
    partial[ct] += __shfl_xor(partial[ct], 32, 64);
  }
  if (lane < 16) {
#pragma unroll
    for (int ct = 0; ct < 8; ct++) red[wave][ct * 16 + lane] = partial[ct];
  }
  __syncthreads();
  if (tid < 128) {
    float s = red[0][tid] + red[1][tid] + red[2][tid] + red[3][tid];
    atomicAdd(&ksum[m * 128 + tid], s);
  }
}

// ---------------- softmax over 2 metapath logits ----------------
__global__ void k_attn(const float* __restrict__ ksum, const float* __restrict__ q,
                       float* __restrict__ attn) {
  __shared__ float red0[128], red1[128];
  int t = threadIdx.x;
  float qv = q[t];
  red0[t] = ksum[t] * qv;
  red1[t] = ksum[128 + t] * qv;
  __syncthreads();
  for (int off = 64; off > 0; off >>= 1) {
    if (t < off) {
      red0[t] += red0[t + off];
      red1[t] += red1[t + off];
    }
    __syncthreads();
  }
  if (t == 0) {
    float l0 = red0[0] / (float)NN, l1 = red1[0] / (float)NN;
    float mx = fmaxf(l0, l1);
    float e0 = __expf(l0 - mx), e1 = __expf(l1 - mx);
    float s = e0 + e1;
    attn[0] = e0 / s;
    attn[1] = e1 / s;
  }
}

// ---------------- fuse + output head ----------------
__global__ __launch_bounds__(256) void k_final(const __hip_bfloat162* __restrict__ h0,
    const __hip_bfloat162* __restrict__ h1, const float* __restrict__ lw,
    const float* __restrict__ lb, const float* __restrict__ attn,
    float* __restrict__ out) {
  const int lane = threadIdx.x & 63;
  const int node = blockIdx.x * 4 + (threadIdx.x >> 6);
  if (node >= NN) return;
  float a0 = attn[0], a1 = attn[1];
  float2 v0 = __bfloat1622float2(h0[(size_t)node * 64 + lane]);
  float2 v1 = __bfloat1622float2(h1[(size_t)node * 64 + lane]);
  float f0 = a0 * v0.x + a1 * v1.x;
  float f1 = a0 * v0.y + a1 * v1.y;
  int i0 = 2 * lane;
  float p[4];
#pragma unroll
  for (int c = 0; c < 4; c++)
    p[c] = f0 * lw[i0 * 4 + c] + f1 * lw[(i0 + 1) * 4 + c];
#pragma unroll
  for (int off = 32; off > 0; off >>= 1) {
#pragma unroll
    for (int c = 0; c < 4; c++) p[c] += __shfl_down(p[c], off, 64);
  }
  if (lane == 0) {
#pragma unroll
    for (int c = 0; c < 4; c++) out[(size_t)node * 4 + c] = p[c] + lb[c];
  }
}

extern "C" void kernel_launch(void* const* d_in, const int* in_sizes, int n_in,
                              void* d_out, int out_size, void* d_ws, size_t ws_size,
                              hipStream_t stream) {
  const float* x      = (const float*)d_in[0];
  const int*   ei0    = (const int*)d_in[1];
  const int*   ei1    = (const int*)d_in[2];
  const float* proj_w = (const float*)d_in[3];
  const float* proj_b = (const float*)d_in[4];
  const float* a0s    = (const float*)d_in[5];
  const float* a0d    = (const float*)d_in[6];
  const float* a1s    = (const float*)d_in[7];
  const float* a1d    = (const float*)d_in[8];
  const float* klw    = (const float*)d_in[9];
  const float* klb    = (const float*)d_in[10];
  const float* q      = (const float*)d_in[11];
  const float* lw     = (const float*)d_in[12];
  const float* lb     = (const float*)d_in[13];
  float* out = (float*)d_out;

  char* ws = (char*)d_ws;
  size_t off = 0;
  auto alloc = [&](size_t bytes) -> void* {
    size_t o = (off + 255) & ~(size_t)255;
    off = o + bytes;
    return (void*)(ws + o);
  };
  __hip_bfloat162* xph = (__hip_bfloat162*)alloc((size_t)NN * 128 * 2);
  __hip_bfloat162* h0  = (__hip_bfloat162*)alloc((size_t)NN * 128 * 2);
  __hip_bfloat162* h1  = (__hip_bfloat162*)alloc((size_t)NN * 128 * 2);
  float* as0  = (float*)alloc((size_t)NN * 8 * 4);
  float* ad0  = (float*)alloc((size_t)NN * 8 * 4);
  float* as1  = (float*)alloc((size_t)NN * 8 * 4);
  float* ad1  = (float*)alloc((size_t)NN * 8 * 4);
  int* cnt    = (int*)alloc((size_t)2 * NN * 4);   // 800000 B (multiple of 256)
  float* ksum = (float*)alloc(256 * 4);            // contiguous after cnt
  float* attn = (float*)alloc(256);
  int* csr    = (int*)alloc((size_t)2 * NN * CAP * 4);

  // zero cnt + ksum in one shot (contiguous layout)
  hipMemsetAsync(cnt, 0, (size_t)2 * NN * 4 + 256 * 4, stream);

  k_proj<<<dim3((NN + 63) / 64), 256, 0, stream>>>(x, proj_w, proj_b, xph);
  k_alpha<<<dim3((NN + 3) / 4), 256, 0, stream>>>(xph, a0s, a0d, a1s, a1d,
                                                  as0, ad0, as1, ad1);
  k_scatter<<<dim3((EE + 255) / 256, 2), 256, 0, stream>>>(ei0, ei1, cnt, csr);
  k_aggr<<<dim3((NN + 3) / 4, 2), 256, 0, stream>>>(xph, as0, ad0, as1, ad1,
                                                    cnt, csr, h0, h1);
  k_sem<<<dim3(SEMGX, 2), 256, 0, stream>>>((const __hip_bfloat16*)h0,
                                            (const __hip_bfloat16*)h1, klw, klb, ksum);
  k_attn<<<dim3(1), 128, 0, stream>>>(ksum, q, attn);
  k_final<<<dim3((NN + 3) / 4), 256, 0, stream>>>(h0, h1, lw, lb, attn, out);
}

// Round 6
// 588.033 us; speedup vs baseline: 1.2894x; 1.2894x over previous
//
#include <hip/hip_runtime.h>
#include <hip/hip_bf16.h>

#define NN 100000
#define EE 1600000
#define HID 128
#define NEG 0.2f
#define CAP 64     // fixed CSR capacity per node (avg deg 16, P(deg>64) ~ 1e-19)
#define BSH 9      // coarse bucket = dst >> 9 (512 nodes/bucket)
#define NB 196     // ceil(NN / 512)
#define CAPB 9216  // per-bucket edge capacity (mean 8192, sigma~90 -> 11 sigma)
#define EBLK 16384 // edges per k_bin block

typedef __attribute__((ext_vector_type(8))) short short8;
typedef __attribute__((ext_vector_type(4))) float f32x4;

// ---------------- projection GEMM: xph = bf16(x @ proj_w + b) ----------------
__global__ __launch_bounds__(256) void k_proj(const float* __restrict__ x,
    const float* __restrict__ w, const float* __restrict__ bias,
    __hip_bfloat162* __restrict__ xph) {
  __shared__ float xs[64][32];
  __shared__ float ws[32][128];
  const int tid = threadIdx.x;
  const int row0 = blockIdx.x * 64;
  const int cb = (tid & 31) * 4;   // col base (0..124)
  const int rb = (tid >> 5) * 8;   // row base (0..56)
  float acc[8][4] = {};
  for (int k0 = 0; k0 < 256; k0 += 32) {
    {
      int f = tid * 8;
      int r = f >> 5, c = f & 31;
      int rg = row0 + r;
      float4 v0 = make_float4(0.f, 0.f, 0.f, 0.f), v1 = v0;
      if (rg < NN) {
        const float4* src = (const float4*)&x[(size_t)rg * 256 + k0 + c];
        v0 = src[0];
        v1 = src[1];
      }
      *(float4*)&xs[r][c] = v0;
      *(float4*)&xs[r][c + 4] = v1;
    }
    {
      int f = tid * 16;
      int r = f >> 7, c = f & 127;
      const float4* src = (const float4*)&w[(size_t)(k0 + r) * 128 + c];
      float4 a0 = src[0], a1 = src[1], a2 = src[2], a3 = src[3];
      *(float4*)&ws[r][c] = a0;
      *(float4*)&ws[r][c + 4] = a1;
      *(float4*)&ws[r][c + 8] = a2;
      *(float4*)&ws[r][c + 12] = a3;
    }
    __syncthreads();
#pragma unroll
    for (int kk = 0; kk < 32; kk++) {
      float4 wv = *(const float4*)&ws[kk][cb];
#pragma unroll
      for (int r = 0; r < 8; r++) {
        float a = xs[rb + r][kk];
        acc[r][0] = fmaf(a, wv.x, acc[r][0]);
        acc[r][1] = fmaf(a, wv.y, acc[r][1]);
        acc[r][2] = fmaf(a, wv.z, acc[r][2]);
        acc[r][3] = fmaf(a, wv.w, acc[r][3]);
      }
    }
    __syncthreads();
  }
  float4 bv = *(const float4*)&bias[cb];
#pragma unroll
  for (int r = 0; r < 8; r++) {
    int rg = row0 + rb + r;
    if (rg < NN) {
      float4 o;
      o.x = acc[r][0] + bv.x;
      o.y = acc[r][1] + bv.y;
      o.z = acc[r][2] + bv.z;
      o.w = acc[r][3] + bv.w;
      __hip_bfloat162 b01 = __float22bfloat162_rn(make_float2(o.x, o.y));
      __hip_bfloat162 b23 = __float22bfloat162_rn(make_float2(o.z, o.w));
      *(uint2*)&xph[(size_t)rg * 64 + (cb >> 1)] =
          make_uint2(*(unsigned*)&b01, *(unsigned*)&b23);
    }
  }
}

// ---------------- per-node attention logits (bf16 xph) ----------------
__global__ __launch_bounds__(256) void k_alpha(const __hip_bfloat162* __restrict__ xph,
    const float* __restrict__ a0s, const float* __restrict__ a0d,
    const float* __restrict__ a1s, const float* __restrict__ a1d,
    float* __restrict__ as0, float* __restrict__ ad0,
    float* __restrict__ as1, float* __restrict__ ad1) {
  const int lane = threadIdx.x & 63;
  const int node = blockIdx.x * 4 + (threadIdx.x >> 6);
  if (node >= NN) return;
  float2 v = __bfloat1622float2(xph[(size_t)node * 64 + lane]);
  int i0 = 2 * lane;
  float p0 = v.x * a0s[i0] + v.y * a0s[i0 + 1];
  float p1 = v.x * a0d[i0] + v.y * a0d[i0 + 1];
  float p2 = v.x * a1s[i0] + v.y * a1s[i0 + 1];
  float p3 = v.x * a1d[i0] + v.y * a1d[i0 + 1];
#pragma unroll
  for (int off = 1; off < 8; off <<= 1) {
    p0 += __shfl_xor(p0, off, 64);
    p1 += __shfl_xor(p1, off, 64);
    p2 += __shfl_xor(p2, off, 64);
    p3 += __shfl_xor(p3, off, 64);
  }
  if ((lane & 7) == 0) {
    int h = lane >> 3;
    as0[node * 8 + h] = p0;
    ad0[node * 8 + h] = p1;
    as1[node * 8 + h] = p2;
    ad1[node * 8 + h] = p3;
  }
}

// ---------------- phase A: bin edges by coarse dst bucket ----------------
// Per-(block,bucket) contiguous runs keep the random writes inside a ~132 KB
// L2-resident window so lines fill before eviction (the r3-r5 scatter's 60 B
// eviction per 4 B store is what we're killing).
__global__ __launch_bounds__(256) void k_bin(const int* __restrict__ ei0,
    const int* __restrict__ ei1, int* __restrict__ gcur, int* __restrict__ binned) {
  const int p = blockIdx.y;
  const int* __restrict__ ei = p ? ei1 : ei0;
  const int* __restrict__ src = ei;
  const int* __restrict__ dst = ei + EE;
  int* __restrict__ gc = gcur + p * 256;
  int* __restrict__ bn = binned + (size_t)p * NB * CAPB;
  __shared__ int cntL[NB], baseL[NB], posL[NB];
  const int t = threadIdx.x;
  const int e0 = blockIdx.x * EBLK;
  const int e1 = min(e0 + EBLK, EE);
  for (int i = t; i < NB; i += 256) { cntL[i] = 0; posL[i] = 0; }
  __syncthreads();
  for (int e = e0 + t; e < e1; e += 256)
    atomicAdd(&cntL[dst[e] >> BSH], 1);
  __syncthreads();
  for (int i = t; i < NB; i += 256)
    baseL[i] = atomicAdd(&gc[i], cntL[i]);
  __syncthreads();
  for (int e = e0 + t; e < e1; e += 256) {
    int d = dst[e];
    int b = d >> BSH;
    int off = baseL[b] + atomicAdd(&posL[b], 1);
    if (off < CAPB) bn[b * CAPB + off] = (src[e] << BSH) | (d & 511);
  }
}

// ---------------- phase B: bucket -> fixed-capacity CSR ----------------
// One block per bucket; random writes confined to a 512*256B = 128 KB window.
__global__ __launch_bounds__(256) void k_build(const int* __restrict__ gcur,
    const int* __restrict__ binned, int* __restrict__ cnt, int* __restrict__ csr) {
  const int p = blockIdx.y, b = blockIdx.x, t = threadIdx.x;
  const int* __restrict__ bn = binned + (size_t)p * NB * CAPB + (size_t)b * CAPB;
  const int n = min(gcur[p * 256 + b], CAPB);
  int* __restrict__ cs = csr + (size_t)p * NN * CAP;
  __shared__ int lc[512];
  lc[t] = 0;
  lc[t + 256] = 0;
  __syncthreads();
  const int node0 = b << BSH;
  for (int i = t; i < n; i += 256) {
    int v = bn[i];
    int ln = v & 511;
    int off = atomicAdd(&lc[ln], 1);
    if (off < CAP) cs[(size_t)(node0 + ln) * CAP + off] = v >> BSH;
  }
  __syncthreads();
  int n0 = node0 + t, n1 = node0 + t + 256;
  if (n0 < NN) cnt[p * NN + n0] = lc[t];
  if (n1 < NN) cnt[p * NN + n1] = lc[t + 256];
}

// ---------------- GAT aggregation: single-pass, one wave per dst node ----------
#define LRELU(t) ((t) > 0.f ? (t) : NEG * (t))

#define EDGE_BODY(sv)                                      \
  {                                                        \
    unsigned s = (unsigned)(sv);                           \
    float t = asrc[s * 8u + h];                            \
    __hip_bfloat162 v = xph[s * 64u + lane];               \
    float al = __expf(LRELU(t + ad));                      \
    denom += al;                                           \
    float2 f = __bfloat1622float2(v);                      \
    a0 = fmaf(al, f.x, a0);                                \
    a1 = fmaf(al, f.y, a1);                                \
  }

__global__ __launch_bounds__(256) void k_aggr(const __hip_bfloat162* __restrict__ xph,
    const float* __restrict__ as0, const float* __restrict__ ad0,
    const float* __restrict__ as1, const float* __restrict__ ad1,
    const int* __restrict__ cnt, const int* __restrict__ csr,
    __hip_bfloat162* __restrict__ h0, __hip_bfloat162* __restrict__ h1) {
  const int p = blockIdx.y;
  const unsigned lane = threadIdx.x & 63;
  const int node = blockIdx.x * 4 + (threadIdx.x >> 6);
  if (node >= NN) return;
  const float* __restrict__ asrc = p ? as1 : as0;
  const float* __restrict__ adst = p ? ad1 : ad0;
  const int* __restrict__ cs = csr + ((size_t)p * NN + node) * CAP;
  __hip_bfloat162* __restrict__ hout = p ? h1 : h0;
  const unsigned h = lane >> 3;
  const float ad = adst[(unsigned)node * 8u + h];
  const int deg = min(cnt[p * NN + node], CAP);

  float denom = 1e-16f, a0 = 0.f, a1 = 0.f;
  int e = 0;
  for (; e + 8 <= deg; e += 8) {
    int4 q0 = *(const int4*)&cs[e];       // wave-uniform, 16B-aligned (CAP layout)
    int4 q1 = *(const int4*)&cs[e + 4];
    EDGE_BODY(q0.x) EDGE_BODY(q0.y) EDGE_BODY(q0.z) EDGE_BODY(q0.w)
    EDGE_BODY(q1.x) EDGE_BODY(q1.y) EDGE_BODY(q1.z) EDGE_BODY(q1.w)
  }
  for (; e + 4 <= deg; e += 4) {
    int4 q0 = *(const int4*)&cs[e];
    EDGE_BODY(q0.x) EDGE_BODY(q0.y) EDGE_BODY(q0.z) EDGE_BODY(q0.w)
  }
  for (; e < deg; e++) EDGE_BODY(cs[e])
  float inv = 1.f / denom;
  hout[(size_t)node * 64 + lane] =
      __float22bfloat162_rn(make_float2(fmaxf(a0 * inv, 0.f), fmaxf(a1 * inv, 0.f)));
}

// ---------------- semantic attention via MFMA ----------------
#define KWS 136
#define NTILES ((NN + 63) / 64)
#define SEMGX 256

__global__ __launch_bounds__(256) void k_sem(const __hip_bfloat16* __restrict__ h0,
    const __hip_bfloat16* __restrict__ h1, const float* __restrict__ kw,
    const float* __restrict__ kb, float* __restrict__ ksum) {
  __shared__ short kwT[128 * KWS];
  __shared__ float red[4][128];
  const int tid = threadIdx.x;
  const int m = blockIdx.y;
  const short* __restrict__ hc = (const short*)(m ? h1 : h0);
  for (int l = tid; l < 128 * 128; l += 256) {
    int i = l >> 7, j = l & 127;   // kw[i][j] -> kwT[j][i]
    __hip_bfloat16 bv = __float2bfloat16(kw[l]);
    kwT[j * KWS + i] = *(short*)&bv;
  }
  const int lane = tid & 63;
  const int wave = tid >> 6;
  const int rowgrp = lane >> 4;
  const int lcol = lane & 15;
  float partial[8] = {};
  float kbv[8];
#pragma unroll
  for (int ct = 0; ct < 8; ct++) kbv[ct] = kb[ct * 16 + lcol];
  __syncthreads();
  for (int tile = blockIdx.x; tile < NTILES; tile += SEMGX) {
    int n0 = tile * 64 + wave * 16;
    int row = n0 + lcol;
    if (row >= NN) row = 0;
    const short* hr = hc + (size_t)row * 128 + rowgrp * 8;
    short8 afrag[4];
#pragma unroll
    for (int kc = 0; kc < 4; kc++) afrag[kc] = *(const short8*)(hr + kc * 32);
#pragma unroll
    for (int ct = 0; ct < 8; ct++) {
      f32x4 acc = {0.f, 0.f, 0.f, 0.f};
#pragma unroll
      for (int kc = 0; kc < 4; kc++) {
        short8 bfrag = *(const short8*)&kwT[(ct * 16 + lcol) * KWS + kc * 32 + rowgrp * 8];
        acc = __builtin_amdgcn_mfma_f32_16x16x32_bf16(afrag[kc], bfrag, acc, 0, 0, 0);
      }
#pragma unroll
      for (int r = 0; r < 4; r++) {
        int node = n0 + rowgrp * 4 + r;
        if (node < NN) partial[ct] += tanhf(acc[r] + kbv[ct]);
      }
    }
  }
#pragma unroll
  for (int ct = 0; ct < 8; ct++) {
    partial[ct] += __shfl_xor(partial[ct], 16, 64);
    partial[ct] += __shfl_xor(partial[ct], 32, 64);
  }
  if (lane < 16) {
#pragma unroll
    for (int ct = 0; ct < 8; ct++) red[wave][ct * 16 + lane] = partial[ct];
  }
  __syncthreads();
  if (tid < 128) {
    float s = red[0][tid] + red[1][tid] + red[2][tid] + red[3][tid];
    atomicAdd(&ksum[m * 128 + tid], s);
  }
}

// ---------------- softmax over 2 metapath logits ----------------
__global__ void k_attn(const float* __restrict__ ksum, const float* __restrict__ q,
                       float* __restrict__ attn) {
  __shared__ float red0[128], red1[128];
  int t = threadIdx.x;
  float qv = q[t];
  red0[t] = ksum[t] * qv;
  red1[t] = ksum[128 + t] * qv;
  __syncthreads();
  for (int off = 64; off > 0; off >>= 1) {
    if (t < off) {
      red0[t] += red0[t + off];
      red1[t] += red1[t + off];
    }
    __syncthreads();
  }
  if (t == 0) {
    float l0 = red0[0] / (float)NN, l1 = red1[0] / (float)NN;
    float mx = fmaxf(l0, l1);
    float e0 = __expf(l0 - mx), e1 = __expf(l1 - mx);
    float s = e0 + e1;
    attn[0] = e0 / s;
    attn[1] = e1 / s;
  }
}

// ---------------- fuse + output head ----------------
__global__ __launch_bounds__(256) void k_final(const __hip_bfloat162* __restrict__ h0,
    const __hip_bfloat162* __restrict__ h1, const float* __restrict__ lw,
    const float* __restrict__ lb, const float* __restrict__ attn,
    float* __restrict__ out) {
  const int lane = threadIdx.x & 63;
  const int node = blockIdx.x * 4 + (threadIdx.x >> 6);
  if (node >= NN) return;
  float a0 = attn[0], a1 = attn[1];
  float2 v0 = __bfloat1622float2(h0[(size_t)node * 64 + lane]);
  float2 v1 = __bfloat1622float2(h1[(size_t)node * 64 + lane]);
  float f0 = a0 * v0.x + a1 * v1.x;
  float f1 = a0 * v0.y + a1 * v1.y;
  int i0 = 2 * lane;
  float p[4];
#pragma unroll
  for (int c = 0; c < 4; c++)
    p[c] = f0 * lw[i0 * 4 + c] + f1 * lw[(i0 + 1) * 4 + c];
#pragma unroll
  for (int off = 32; off > 0; off >>= 1) {
#pragma unroll
    for (int c = 0; c < 4; c++) p[c] += __shfl_down(p[c], off, 64);
  }
  if (lane == 0) {
#pragma unroll
    for (int c = 0; c < 4; c++) out[(size_t)node * 4 + c] = p[c] + lb[c];
  }
}

extern "C" void kernel_launch(void* const* d_in, const int* in_sizes, int n_in,
                              void* d_out, int out_size, void* d_ws, size_t ws_size,
                              hipStream_t stream) {
  const float* x      = (const float*)d_in[0];
  const int*   ei0    = (const int*)d_in[1];
  const int*   ei1    = (const int*)d_in[2];
  const float* proj_w = (const float*)d_in[3];
  const float* proj_b = (const float*)d_in[4];
  const float* a0s    = (const float*)d_in[5];
  const float* a0d    = (const float*)d_in[6];
  const float* a1s    = (const float*)d_in[7];
  const float* a1d    = (const float*)d_in[8];
  const float* klw    = (const float*)d_in[9];
  const float* klb    = (const float*)d_in[10];
  const float* q      = (const float*)d_in[11];
  const float* lw     = (const float*)d_in[12];
  const float* lb     = (const float*)d_in[13];
  float* out = (float*)d_out;

  char* ws = (char*)d_ws;
  size_t off = 0;
  auto alloc = [&](size_t bytes) -> void* {
    size_t o = (off + 255) & ~(size_t)255;
    off = o + bytes;
    return (void*)(ws + o);
  };
  __hip_bfloat162* xph = (__hip_bfloat162*)alloc((size_t)NN * 128 * 2);
  __hip_bfloat162* h0  = (__hip_bfloat162*)alloc((size_t)NN * 128 * 2);
  __hip_bfloat162* h1  = (__hip_bfloat162*)alloc((size_t)NN * 128 * 2);
  float* as0  = (float*)alloc((size_t)NN * 8 * 4);
  float* ad0  = (float*)alloc((size_t)NN * 8 * 4);
  float* as1  = (float*)alloc((size_t)NN * 8 * 4);
  float* ad1  = (float*)alloc((size_t)NN * 8 * 4);
  int* cnt    = (int*)alloc((size_t)2 * NN * 4);   // 800000 B (multiple of 256)
  float* ksum = (float*)alloc(256 * 4);            // contiguous after cnt
  int* gcur   = (int*)alloc(2 * 256 * 4);          // contiguous after ksum
  float* attn = (float*)alloc(256);
  int* csr    = (int*)alloc((size_t)2 * NN * CAP * 4);
  int* binned = (int*)alloc((size_t)2 * NB * CAPB * 4);

  // zero cnt + ksum + gcur in one shot (contiguous layout)
  hipMemsetAsync(cnt, 0, (size_t)2 * NN * 4 + 256 * 4 + 2 * 256 * 4, stream);

  k_proj<<<dim3((NN + 63) / 64), 256, 0, stream>>>(x, proj_w, proj_b, xph);
  k_alpha<<<dim3((NN + 3) / 4), 256, 0, stream>>>(xph, a0s, a0d, a1s, a1d,
                                                  as0, ad0, as1, ad1);
  k_bin<<<dim3((EE + EBLK - 1) / EBLK, 2), 256, 0, stream>>>(ei0, ei1, gcur, binned);
  k_build<<<dim3(NB, 2), 256, 0, stream>>>(gcur, binned, cnt, csr);
  k_aggr<<<dim3((NN + 3) / 4, 2), 256, 0, stream>>>(xph, as0, ad0, as1, ad1,
                                                    cnt, csr, h0, h1);
  k_sem<<<dim3(SEMGX, 2), 256, 0, stream>>>((const __hip_bfloat16*)h0,
                                            (const __hip_bfloat16*)h1, klw, klb, ksum);
  k_attn<<<dim3(1), 128, 0, stream>>>(ksum, q, attn);
  k_final<<<dim3((NN + 3) / 4), 256, 0, stream>>>(h0, h1, lw, lb, attn, out);
}